// Round 2
// baseline (297.181 us; speedup 1.0000x reference)
//
#include <hip/hip_runtime.h>

#define BB 8
#define HH 512
#define WW 512
#define K2 9
#define HW (HH * WW)

// 8-byte pair with 4-byte alignment: lets the backend emit an (unaligned)
// dwordx2, or worst case two adjacent dword loads in the same cache line.
struct f2 { float lo, hi; };

// Bilinear sample with zero-padding semantics (clamp the load, mask the
// contribution). Two 8B row loads instead of four scalar gathers.
__device__ __forceinline__ float bil(const float* __restrict__ dimg,
                                     float py, float px) {
    const float y0f = floorf(py);
    const float x0f = floorf(px);
    const float ty = py - y0f;
    const float tx = px - x0f;
    const int y0 = (int)y0f;
    const int x0 = (int)x0f;
    const int y1 = y0 + 1;
    const int x1 = x0 + 1;

    const int y0c = min(max(y0, 0), HH - 1);
    const int y1c = min(max(y1, 0), HH - 1);
    const int xl  = min(max(x0, 0), WW - 2);   // pair base

    const f2 top = *(const f2*)(dimg + y0c * WW + xl);
    const f2 bot = *(const f2*)(dimg + y1c * WW + xl);

    // x0 == xl  <=> x0 in [0, W-2]  => (v00,v01) = (lo,hi); else swapped
    const bool sw = (x0 != xl);
    const float v00 = sw ? top.hi : top.lo;
    const float v01 = sw ? top.lo : top.hi;
    const float v10 = sw ? bot.hi : bot.lo;
    const float v11 = sw ? bot.lo : bot.hi;

    const bool vy0 = (y0 >= 0) & (y0 < HH);
    const bool vy1 = (y1 >= 0) & (y1 < HH);
    const bool vx0 = (x0 >= 0) & (x0 < WW);
    const bool vx1 = (x1 >= 0) & (x1 < WW);

    const float w00 = (vy0 & vx0) ? (1.f - ty) * (1.f - tx) : 0.f;
    const float w01 = (vy0 & vx1) ? (1.f - ty) * tx         : 0.f;
    const float w10 = (vy1 & vx0) ? ty * (1.f - tx)         : 0.f;
    const float w11 = (vy1 & vx1) ? ty * tx                 : 0.f;

    return v00 * w00 + v01 * w01 + v10 * w10 + v11 * w11;
}

__global__ __launch_bounds__(256, 4) void pp_deconv_kernel(
    const float* __restrict__ depth,   // (B,1,H,W)
    const float* __restrict__ weight,  // (B,K2,H,W)
    const float* __restrict__ offset,  // (B,2*K2,H,W)
    float* __restrict__ out)           // (B,1,H,W)
{
    const int t = blockIdx.x * blockDim.x + threadIdx.x;  // 4 pixels/thread
    const int idx = t << 2;
    const int b = idx >> 18;          // / HW
    const int p = idx & (HW - 1);
    const int y = p >> 9;             // / W
    const int x = p & (WW - 1);       // multiple of 4; x..x+3 in same row

    const float* wp   = weight + (size_t)b * K2 * HW + p;
    const float* op   = offset + (size_t)b * 2 * K2 * HW + p;
    const float* dimg = depth  + (size_t)b * HW;

    // ---- weights (float4 per plane) + mean ----
    float4 w4[K2];
    float4 ws = make_float4(0.f, 0.f, 0.f, 0.f);
#pragma unroll
    for (int k = 0; k < K2; ++k) {
        w4[k] = *(const float4*)(wp + k * HW);
        ws.x += w4[k].x; ws.y += w4[k].y; ws.z += w4[k].z; ws.w += w4[k].w;
    }
    const float c = 1.0f / 9.0f;
    const float4 wm = make_float4(ws.x * c, ws.y * c, ws.z * c, ws.w * c);

    float4 acc = make_float4(0.f, 0.f, 0.f, 0.f);
#pragma unroll
    for (int k = 0; k < K2; ++k) {
        const int ky = k / 3;
        const int kx = k % 3;
        const float4 dy4 = *(const float4*)(op + (2 * k) * HW);
        const float4 dx4 = *(const float4*)(op + (2 * k + 1) * HW);

        const float ybase = (float)(y - 1 + ky);
        const float xbase = (float)(x - 1 + kx);

        acc.x += bil(dimg, dy4.x + ybase, dx4.x + xbase + 0.f) * (w4[k].x - wm.x);
        acc.y += bil(dimg, dy4.y + ybase, dx4.y + xbase + 1.f) * (w4[k].y - wm.y);
        acc.z += bil(dimg, dy4.z + ybase, dx4.z + xbase + 2.f) * (w4[k].z - wm.z);
        acc.w += bil(dimg, dy4.w + ybase, dx4.w + xbase + 3.f) * (w4[k].w - wm.w);
    }

    const float4 d0 = *(const float4*)(dimg + p);
    float4 o;
    o.x = acc.x + d0.x;
    o.y = acc.y + d0.y;
    o.z = acc.z + d0.z;
    o.w = acc.w + d0.w;
    *(float4*)(out + idx) = o;
}

extern "C" void kernel_launch(void* const* d_in, const int* in_sizes, int n_in,
                              void* d_out, int out_size, void* d_ws, size_t ws_size,
                              hipStream_t stream) {
    const float* depth  = (const float*)d_in[0];
    const float* weight = (const float*)d_in[1];
    const float* offset = (const float*)d_in[2];
    float* out = (float*)d_out;

    const int total_threads = BB * HW / 4;
    const int block = 256;
    const int grid = total_threads / block;
    pp_deconv_kernel<<<grid, block, 0, stream>>>(depth, weight, offset, out);
}

// Round 3
// 277.776 us; speedup vs baseline: 1.0699x; 1.0699x over previous
//
#include <hip/hip_runtime.h>

#define BB 8
#define HH 512
#define WW 512
#define K2 9
#define HW (HH * WW)

// Tile geometry: each block computes a TY x TX pixel tile.
// LDS stages depth rows [ty0-5, ty0+TY+5] x cols [tx0-5, tx0+TX+5]
// (halo covers |offset| <= 4; rare tail falls back to global).
#define TX 64
#define TY 16
#define NROWS (TY + 11)   // 27
#define NCOLS (TX + 11)   // 75
#define STRIDE (NCOLS + 1) // 76, breaks pow2 banking

// Global fallback with reference clamp+mask semantics (rare path).
__device__ __noinline__ float gsample(const float* __restrict__ dimg,
                                      float py, float px) {
    const float y0f = floorf(py);
    const float x0f = floorf(px);
    const float ty = py - y0f;
    const float tx = px - x0f;
    const int y0 = (int)y0f, x0 = (int)x0f;
    const int y1 = y0 + 1,   x1 = x0 + 1;
    const int y0c = min(max(y0, 0), HH - 1);
    const int y1c = min(max(y1, 0), HH - 1);
    const int x0c = min(max(x0, 0), WW - 1);
    const int x1c = min(max(x1, 0), WW - 1);
    const float v00 = dimg[y0c * WW + x0c];
    const float v01 = dimg[y0c * WW + x1c];
    const float v10 = dimg[y1c * WW + x0c];
    const float v11 = dimg[y1c * WW + x1c];
    const bool vy0 = (unsigned)y0 < HH, vy1 = (unsigned)y1 < HH;
    const bool vx0 = (unsigned)x0 < WW, vx1 = (unsigned)x1 < WW;
    const float w00 = (vy0 & vx0) ? (1.f - ty) * (1.f - tx) : 0.f;
    const float w01 = (vy0 & vx1) ? (1.f - ty) * tx         : 0.f;
    const float w10 = (vy1 & vx0) ? ty * (1.f - tx)         : 0.f;
    const float w11 = (vy1 & vx1) ? ty * tx                 : 0.f;
    return v00 * w00 + v01 * w01 + v10 * w10 + v11 * w11;
}

__global__ __launch_bounds__(256, 4) void pp_deconv_kernel(
    const float* __restrict__ depth,   // (B,1,H,W)
    const float* __restrict__ weight,  // (B,K2,H,W)
    const float* __restrict__ offset,  // (B,2*K2,H,W)
    float* __restrict__ out)           // (B,1,H,W)
{
    __shared__ float tile[NROWS * STRIDE];

    const int tid = threadIdx.x;
    const int tx0 = blockIdx.x * TX;
    const int ty0 = blockIdx.y * TY;
    const int b   = blockIdx.z;

    const int ry0 = ty0 - 5;   // global row of tile row 0
    const int cx0 = tx0 - 5;   // global col of tile col 0

    const float* dimg = depth + (size_t)b * HW;

    // ---- stage depth tile + halo; zero outside image (== reference mask) ----
    for (int li = tid; li < NROWS * NCOLS; li += 256) {
        const int r = li / NCOLS;
        const int c = li - r * NCOLS;
        const int gy = ry0 + r;
        const int gx = cx0 + c;
        float v = 0.f;
        if ((unsigned)gy < HH && (unsigned)gx < WW) v = dimg[gy * WW + gx];
        tile[r * STRIDE + c] = v;
    }
    __syncthreads();

    // ---- 4 x-consecutive pixels per thread ----
    const int xl = (tid & 15) << 2;   // 0..60
    const int yl = tid >> 4;          // 0..15
    const int x = tx0 + xl;
    const int y = ty0 + yl;
    const int p = y * WW + x;

    const float* wp = weight + (size_t)b * K2 * HW + p;
    const float* op = offset + (size_t)b * 2 * K2 * HW + p;

    float4 accw = make_float4(0.f, 0.f, 0.f, 0.f);
    float4 accs = make_float4(0.f, 0.f, 0.f, 0.f);
    float4 wsum = make_float4(0.f, 0.f, 0.f, 0.f);

#pragma unroll
    for (int k = 0; k < K2; ++k) {
        const int ky = k / 3;
        const int kx = k % 3;
        const float4 w4  = *(const float4*)(wp + k * HW);
        const float4 dy4 = *(const float4*)(op + (2 * k) * HW);
        const float4 dx4 = *(const float4*)(op + (2 * k + 1) * HW);

        const float ybase = (float)(y - 1 + ky);
        const float xbase = (float)(x - 1 + kx);

        float s[4];
        const float pys[4] = {dy4.x + ybase, dy4.y + ybase, dy4.z + ybase, dy4.w + ybase};
        const float pxs[4] = {dx4.x + xbase, dx4.y + xbase + 1.f,
                              dx4.z + xbase + 2.f, dx4.w + xbase + 3.f};
#pragma unroll
        for (int j = 0; j < 4; ++j) {
            const float py = pys[j], px = pxs[j];
            const float y0f = floorf(py);
            const float x0f = floorf(px);
            const float ty = py - y0f;
            const float tx = px - x0f;
            const int iy = (int)y0f - ry0;   // tile row of top corner
            const int ix = (int)x0f - cx0;   // tile col of left corner
            if ((unsigned)iy < NROWS - 1 && (unsigned)ix < NCOLS - 1) {
                const float* q = tile + iy * STRIDE + ix;
                const float v00 = q[0], v01 = q[1];
                const float v10 = q[STRIDE], v11 = q[STRIDE + 1];
                const float a0 = v00 + tx * (v01 - v00);
                const float a1 = v10 + tx * (v11 - v10);
                s[j] = a0 + ty * (a1 - a0);
            } else {
                s[j] = gsample(dimg, py, px);
            }
        }
        accw.x += s[0] * w4.x;  accs.x += s[0];  wsum.x += w4.x;
        accw.y += s[1] * w4.y;  accs.y += s[1];  wsum.y += w4.y;
        accw.z += s[2] * w4.z;  accs.z += s[2];  wsum.z += w4.z;
        accw.w += s[3] * w4.w;  accs.w += s[3];  wsum.w += w4.w;
    }

    // residual depth from LDS (always in-tile, in-image)
    const float* dq = tile + (yl + 5) * STRIDE + (xl + 5);
    const float c9 = 1.0f / 9.0f;
    float4 o;
    o.x = accw.x - wsum.x * c9 * accs.x + dq[0];
    o.y = accw.y - wsum.y * c9 * accs.y + dq[1];
    o.z = accw.z - wsum.z * c9 * accs.z + dq[2];
    o.w = accw.w - wsum.w * c9 * accs.w + dq[3];
    *(float4*)(out + (size_t)b * HW + p) = o;
}

extern "C" void kernel_launch(void* const* d_in, const int* in_sizes, int n_in,
                              void* d_out, int out_size, void* d_ws, size_t ws_size,
                              hipStream_t stream) {
    const float* depth  = (const float*)d_in[0];
    const float* weight = (const float*)d_in[1];
    const float* offset = (const float*)d_in[2];
    float* out = (float*)d_out;

    dim3 grid(WW / TX, HH / TY, BB);   // 8 x 32 x 8 = 2048 blocks
    dim3 block(256);
    pp_deconv_kernel<<<grid, block, 0, stream>>>(depth, weight, offset, out);
}